// Round 1
// baseline (302.443 us; speedup 1.0000x reference)
//
#include <hip/hip_runtime.h>
#include <hip/hip_bf16.h>

using bf16 = __hip_bfloat16;
typedef unsigned short ushort_t;
typedef unsigned int uint_t;

constexpr int B = 2, T = 200;
constexpr int N0 = 2048, N1 = 512, N2 = 128, N3 = 64;
constexpr int E0 = 16384, E1 = 8192, E2 = 2048;

typedef __attribute__((ext_vector_type(8))) short bf16x8;
typedef __attribute__((ext_vector_type(4))) float f32x4;

// ---- workspace byte offsets (shared host/device) ----
constexpr size_t O_FLAG = 161792;   // int flag (outside the zeroed 40448-int region)
constexpr size_t O_WC1  = 163840;   // 64 f
constexpr size_t O_BIAS = 164096;   // 304 f: b1@0 b2@16 b3@48 b1h@112 b2h@240
constexpr size_t O_BW0  = 165312;   // 49152 f
constexpr size_t O_BW1  = 361920;   // 24576 f
constexpr size_t O_BW2  = 460224;   // 6144 f
constexpr size_t O_PB1  = 484800;   // 1048576 u16
constexpr size_t O_PB2  = 2581952;  // 65536 u16
constexpr size_t O_PB3  = 2713024;  // 8192 u16
constexpr size_t O_WT2  = 2729408;  // 2048 u16  [O=32][C=64]
constexpr size_t O_WT3  = 2733504;  // 8192 u16  [O=64][C=128]
constexpr size_t O_W1H  = 2749888;  // 8192 u16  [O=128][C=64]
constexpr size_t O_W2H  = 2766272;  // 8192 u16  [O=64][C=128]
constexpr size_t O_AA   = 2785280;  // arena A 13,107,200 B (fp32 hp)
constexpr size_t O_BB   = 15892480; // arena B 26,214,400 B (bf16 h)

__device__ __forceinline__ float ldx(const void* p, long i, int bf) {
  if (bf) {
    uint_t v = (uint_t)(((const ushort_t*)p)[i]) << 16;
    float f; __builtin_memcpy(&f, &v, 4); return f;
  }
  return ((const float*)p)[i];
}
__device__ __forceinline__ void stf(float* p, float v) { *p = v; }
__device__ __forceinline__ void stf(bf16* p, float v) { *p = __float2bfloat16(v); }
__device__ __forceinline__ ushort_t f2bfu(float v) {
  bf16 h = __float2bfloat16(v); ushort_t u; __builtin_memcpy(&u, &h, 2); return u;
}

struct InPtrs {
  const void* ea0; const void* ea1; const void* ea2;
  const void* P01; const void* P12; const void* P23;
  const void* Wk1; const void* Wr1; const void* Wk2; const void* Wr2;
  const void* Wk3; const void* Wr3; const void* W1h; const void* W2h;
  const void* b1; const void* b2; const void* b3; const void* b1h; const void* b2h;
  const void* A1; const void* A2; const void* A3;
};

// ---------- setup0: zero CSR ints (blocks 0..157) + dtype probe (block 158) ----------
__global__ void k_setup0(int* I, const ushort_t* ea) {
  if (blockIdx.x < 158) {
    int i = blockIdx.x * 256 + threadIdx.x;
    I[i] = 0;                      // covers 40448 ints exactly
  } else if (threadIdx.x == 0) {
    int c = 0;
    for (int i = 0; i < 128; ++i) {
      uint_t v = (uint_t)ea[i] << 16;
      float f; __builtin_memcpy(&f, &v, 4);
      if (f >= 0.f && f <= 1.0f) c++;
    }
    *(int*)((char*)I + O_FLAG) = (c >= 120) ? 1 : 0;
  }
}

__device__ __forceinline__ void bw_one(const void* ea, int bf, const void* A,
                                       float* bw, int e) {
  float a0 = ldx(ea, e*3+0, bf), a1 = ldx(ea, e*3+1, bf), a2 = ldx(ea, e*3+2, bf);
  float l0 = a0*ldx(A,0,bf) + a1*ldx(A,3,bf) + a2*ldx(A,6,bf);
  float l1 = a0*ldx(A,1,bf) + a1*ldx(A,4,bf) + a2*ldx(A,7,bf);
  float l2 = a0*ldx(A,2,bf) + a1*ldx(A,5,bf) + a2*ldx(A,8,bf);
  float m = fmaxf(l0, fmaxf(l1, l2));
  float x0 = expf(l0 - m), x1 = expf(l1 - m), x2 = expf(l2 - m);
  float inv = 1.0f / (x0 + x1 + x2);
  bw[e*3+0] = x0*inv; bw[e*3+1] = x1*inv; bw[e*3+2] = x2*inv;
}

// ---------- fat prep kernel: edge softmax, P->bf16, W transposes, params ----------
__global__ void k_prep(InPtrs P, char* base) {
  int bf = *(const int*)(base + O_FLAG);
  int bx = blockIdx.x, tid = threadIdx.x;
  float* bw0 = (float*)(base + O_BW0);
  float* bw1 = (float*)(base + O_BW1);
  float* bw2 = (float*)(base + O_BW2);
  if (bx < 64)        { bw_one(P.ea0, bf, P.A1, bw0, bx*256+tid); return; }
  if (bx < 96)        { bw_one(P.ea1, bf, P.A2, bw1, (bx-64)*256+tid); return; }
  if (bx < 104)       { bw_one(P.ea2, bf, P.A3, bw2, (bx-96)*256+tid); return; }
  if (bx < 4200)      { long i = (long)(bx-104)*256+tid;
                        ((ushort_t*)(base+O_PB1))[i] = f2bfu(ldx(P.P01, i, bf)); return; }
  if (bx < 4456)      { int i = (bx-4200)*256+tid;
                        ((ushort_t*)(base+O_PB2))[i] = f2bfu(ldx(P.P12, i, bf)); return; }
  if (bx < 4488)      { int i = (bx-4456)*256+tid;
                        ((ushort_t*)(base+O_PB3))[i] = f2bfu(ldx(P.P23, i, bf)); return; }
  if (bx < 4496)      { int j = (bx-4488)*256+tid; int o = j>>6, c = j&63;
                        float v = (c<48) ? ldx(P.Wk2, c*32+o, bf) : ldx(P.Wr2, (c-48)*32+o, bf);
                        ((ushort_t*)(base+O_WT2))[j] = f2bfu(v); return; }
  if (bx < 4528)      { int j = (bx-4496)*256+tid; int o = j>>7, c = j&127;
                        float v = (c<96) ? ldx(P.Wk3, c*64+o, bf) : ldx(P.Wr3, (c-96)*64+o, bf);
                        ((ushort_t*)(base+O_WT3))[j] = f2bfu(v); return; }
  if (bx < 4560)      { int j = (bx-4528)*256+tid; int o = j>>6, c = j&63;
                        ((ushort_t*)(base+O_W1H))[j] = f2bfu(ldx(P.W1h, c*128+o, bf)); return; }
  if (bx < 4592)      { int j = (bx-4560)*256+tid; int o = j>>7, c = j&127;
                        ((ushort_t*)(base+O_W2H))[j] = f2bfu(ldx(P.W2h, c*64+o, bf)); return; }
  { // params: wc1 (64) + biases (304)
    int i = (bx-4592)*256+tid;
    if (i < 64) {
      ((float*)(base+O_WC1))[i] = (i<48) ? ldx(P.Wk1, i, bf) : ldx(P.Wr1, i-48, bf);
    } else if (i < 368) {
      int j = i - 64; float v;
      if (j < 16)       v = ldx(P.b1, j, bf);
      else if (j < 48)  v = ldx(P.b2, j-16, bf);
      else if (j < 112) v = ldx(P.b3, j-48, bf);
      else if (j < 240) v = ldx(P.b1h, j-112, bf);
      else              v = ldx(P.b2h, j-240, bf);
      ((float*)(base+O_BIAS))[j] = v;
    }
  }
}

__global__ void k_hist3(const int* d0, const int* d1, const int* d2,
                        int* c0, int* c1, int* c2) {
  int i = blockIdx.x * 256 + threadIdx.x;
  if (i < E0) atomicAdd(&c0[d0[i]], 1);
  if (i < E1) atomicAdd(&c1[d1[i]], 1);
  if (i < E2) atomicAdd(&c2[d2[i]], 1);
}

__global__ void k_scan3(const int* c0, int* o0, int* u0,
                        const int* c1, int* o1, int* u1,
                        const int* c2, int* o2, int* u2) {
  const int* cnt; int* off; int* cur; int N;
  if (blockIdx.x == 0)      { cnt = c0; off = o0; cur = u0; N = N0; }
  else if (blockIdx.x == 1) { cnt = c1; off = o1; cur = u1; N = N1; }
  else                      { cnt = c2; off = o2; cur = u2; N = N2; }
  int tid = threadIdx.x;
  int chunk = (N + 63) >> 6;
  int base = tid * chunk;
  int s = 0;
  for (int j = 0; j < chunk; ++j) { int idx = base + j; if (idx < N) s += cnt[idx]; }
  int pre = s;
  for (int d = 1; d < 64; d <<= 1) {
    int v = __shfl_up(pre, d, 64);
    if (tid >= d) pre += v;
  }
  int run = pre - s;
  for (int j = 0; j < chunk; ++j) {
    int idx = base + j;
    if (idx < N) { off[idx] = run; cur[idx] = run; run += cnt[idx]; }
  }
  if (tid == 63) off[N] = run;
}

__global__ void k_fill3(const int* d0, int* u0, int* e0l,
                        const int* d1, int* u1, int* e1l,
                        const int* d2, int* u2, int* e2l) {
  int i = blockIdx.x * 256 + threadIdx.x;
  if (i < E0) { int p = atomicAdd(&u0[d0[i]], 1); e0l[p] = i; }
  if (i < E1) { int p = atomicAdd(&u1[d1[i]], 1); e1l[p] = i; }
  if (i < E2) { int p = atomicAdd(&u2[d2[i]], 1); e2l[p] = i; }
}

// ---------- fused level-1 gather + channel-mix (Cin=1 -> 16), raw x via ldx ----------
// edge data staged in LDS per block (chunks of 32, uniform trip count)
__global__ __launch_bounds__(256) void k_gc1(const void* x, const int* src,
    const int* off, const int* elist, const int* cnt, const float* bw,
    const float* W, const float* bias, bf16* h1, const int* flagp) {
  __shared__ float Wl[64];
  __shared__ float bl[16];
  __shared__ float ew0[32], ew1[32], ew2[32];
  __shared__ int es[32];
  int tid = threadIdx.x;
  if (tid < 64) Wl[tid] = W[tid];
  if (tid < 16) bl[tid] = bias[tid];
  int bf = *flagp;
  int n = blockIdx.y, b = blockIdx.z;
  int t = tid;
  bool tok = t < T;
  int beg = off[n], end = off[n + 1];
  float a0 = 0.f, a1 = 0.f, a2 = 0.f;
  for (int q0 = beg; q0 < end; q0 += 32) {
    int m = end - q0; if (m > 32) m = 32;
    __syncthreads();
    if (tid < m) {
      int e = elist[q0 + tid];
      es[tid] = src[e];
      ew0[tid] = bw[e*3+0]; ew1[tid] = bw[e*3+1]; ew2[tid] = bw[e*3+2];
    }
    __syncthreads();
    if (tok) {
      for (int j = 0; j < m; ++j) {
        float xv = ldx(x, (long)(b * N0 + es[j]) * T + t, bf);
        a0 += ew0[j] * xv; a1 += ew1[j] * xv; a2 += ew2[j] * xv;
      }
    }
  }
  __syncthreads();   // Wl/bl visibility even when the edge loop has 0 iterations
  if (!tok) return;
  int c = cnt[n];
  float inv = 1.f / (float)(c > 0 ? c : 1);
  a0 *= inv; a1 *= inv; a2 *= inv;
  float xr = ldx(x, (long)(b * N0 + n) * T + t, bf);
  bf16* op = h1 + ((long)(b * N0 + n) * 16) * T + t;
#pragma unroll
  for (int o = 0; o < 16; ++o) {
    float v = a0 * Wl[o] + a1 * Wl[16 + o] + a2 * Wl[32 + o] + xr * Wl[48 + o] + bl[o];
    v = v > 0.f ? v : (expf(v) - 1.f);
    op[o * T] = __float2bfloat16(v);
  }
}

// ---------- fused gather + MFMA channel-mix (levels 2,3) ----------
// hp fp32 [B][N][CIN][T] -> h bf16 [B][N][O][T];  C=4*CIN
template<int CIN, int CPI, int O>
__global__ __launch_bounds__(256) void k_gcm(const float* hp, const int* src,
    const int* off, const int* elist, const int* cnt, const float* bw,
    const ushort_t* Wt, const float* bias, bf16* h, int N) {
  constexpr int C = 4 * CIN;
  constexpr int KG = C / 8;
  constexpr int MT = O / 16;
  __shared__ __align__(16) ushort_t Ws[O * C];
  __shared__ __align__(16) ushort_t Is[64 * C];
  __shared__ float ew0[32], ew1[32], ew2[32];
  __shared__ int es[32];
  int tid = threadIdx.x;
  int w = tid >> 6, l = tid & 63;
  int lf = l & 15, quad = l >> 4;
  int t0 = blockIdx.x * 64;
  int n = blockIdx.y, b = blockIdx.z;
  // stage W
  {
    const uint4* Wg = (const uint4*)Wt;
    for (int s = tid; s < O * KG; s += 256) {
      int o = s / KG, kg = s % KG;
      *(uint4*)(Ws + o * C + ((kg ^ (o & 7)) * 8)) = Wg[s];
    }
  }
  // gather into registers, edge data staged in LDS
  int tx = tid & 63, iy = tid >> 6;
  int t = t0 + tx;
  bool tok = t < T;
  float acc[3][CPI], xr[CPI];
#pragma unroll
  for (int k = 0; k < 3; ++k)
#pragma unroll
    for (int j = 0; j < CPI; ++j) acc[k][j] = 0.f;
#pragma unroll
  for (int j = 0; j < CPI; ++j) xr[j] = 0.f;
  int beg = off[n], end = off[n + 1];
  for (int q0 = beg; q0 < end; q0 += 32) {
    int mE = end - q0; if (mE > 32) mE = 32;
    __syncthreads();
    if (tid < mE) {
      int e = elist[q0 + tid];
      es[tid] = src[e];
      ew0[tid] = bw[e*3+0]; ew1[tid] = bw[e*3+1]; ew2[tid] = bw[e*3+2];
    }
    __syncthreads();
    if (tok) {
      for (int j2 = 0; j2 < mE; ++j2) {
        int s = es[j2];
        float w0 = ew0[j2], w1 = ew1[j2], w2 = ew2[j2];
        const float* xp = hp + ((long)(b * N + s) * CIN) * T + t;
#pragma unroll
        for (int j = 0; j < CPI; ++j) {
          float xv = xp[(iy * CPI + j) * T];
          acc[0][j] += w0 * xv; acc[1][j] += w1 * xv; acc[2][j] += w2 * xv;
        }
      }
    }
  }
  float inv = 1.f;
  if (tok) {
    int c = cnt[n];
    inv = 1.f / (float)(c > 0 ? c : 1);
    const float* xs = hp + ((long)(b * N + n) * CIN) * T + t;
#pragma unroll
    for (int j = 0; j < CPI; ++j) xr[j] = xs[(iy * CPI + j) * T];
  }
  // dump z|x into swizzled Is (bf16 scalars)
#pragma unroll
  for (int j = 0; j < CPI; ++j) {
    int i = iy * CPI + j;
#pragma unroll
    for (int k = 0; k < 3; ++k) {
      int c = k * CIN + i;
      Is[tx * C + ((c >> 3) ^ (tx & 7)) * 8 + (c & 7)] = f2bfu(acc[k][j] * inv);
    }
    int c = 3 * CIN + i;
    Is[tx * C + ((c >> 3) ^ (tx & 7)) * 8 + (c & 7)] = f2bfu(xr[j]);
  }
  __syncthreads();
  // MFMA
  f32x4 dacc[MT];
#pragma unroll
  for (int mt = 0; mt < MT; ++mt) dacc[mt] = (f32x4){0.f, 0.f, 0.f, 0.f};
  int tr = w * 16 + lf;
#pragma unroll
  for (int kc = 0; kc < C / 32; ++kc) {
    int kg0 = kc * 4 + quad;
    bf16x8 bfr = *(const bf16x8*)(Is + tr * C + ((kg0 ^ (tr & 7)) * 8));
#pragma unroll
    for (int mt = 0; mt < MT; ++mt) {
      int o = mt * 16 + lf;
      bf16x8 afr = *(const bf16x8*)(Ws + o * C + ((kg0 ^ (o & 7)) * 8));
      dacc[mt] = __builtin_amdgcn_mfma_f32_16x16x32_bf16(afr, bfr, dacc[mt], 0, 0, 0);
    }
  }
  int tg = t0 + w * 16 + lf;
  if (tg < T) {
    long nb = (long)(b * N + n) * O;
#pragma unroll
    for (int mt = 0; mt < MT; ++mt) {
#pragma unroll
      for (int r = 0; r < 4; ++r) {
        int o = mt * 16 + quad * 4 + r;
        float v = dacc[mt][r] + bias[o];
        v = v > 0.f ? v : (expf(v) - 1.f);
        h[(nb + o) * T + tg] = __float2bfloat16(v);
      }
    }
  }
}

// ---------- pipelined pool GEMM: out[b,m,f] (+)= sum_k Pb[m,k] * h[b,k,f] ----------
// BM=64, BN=64; register double-buffer prefetch; split-K via atomicAdd; XCD swizzle.
// grid.x = (F/64) * (M/64) * KSPLIT * B, linearized; nInner = (M/64)*KSPLIT*B
template<int KSPLIT, bool ATOMIC, bool SWZ>
__global__ __launch_bounds__(256) void k_poolp(const ushort_t* Pb, const ushort_t* h,
                                               float* out, int M, int K, int F, int nInner) {
  __shared__ __align__(16) ushort_t As[64 * 64];
  __shared__ __align__(16) ushort_t Bs[64 * 64];
  int tid = threadIdx.x;
  int w = tid >> 6, l = tid & 63;
  int lf = l & 15, quad = l >> 4;
  int v = blockIdx.x;
  if (SWZ) { int q = gridDim.x >> 3; v = (v & 7) * q + (v >> 3); }  // f-chunk per XCD
  int f_blk = v / nInner; int rem = v % nInner;
  int m_blk = rem / (KSPLIT * B);
  int kc = (rem / B) % KSPLIT;
  int b = rem % B;
  int f0 = f_blk * 64, m0 = m_blk * 64;
  int Kc = K / KSPLIT;
  int k0 = kc * Kc;
  int nsteps = Kc >> 6;   // even for all uses (16 / 4 / 2)

  // per-thread staging addresses
  int am0 = tid >> 3, ak = tid & 7;        // A rows: 2 uint4/thread
  int am1 = am0 + 32;
  const ushort_t* Ap0 = Pb + (long)(m0 + am0) * K + k0 + ak * 8;
  const ushort_t* Ap1 = Pb + (long)(m0 + am1) * K + k0 + ak * 8;
  int fB = tid & 63, kb = (tid >> 6) * 16; // B: 16 scalar ushort/thread (f fixed, k strided)
  const ushort_t* Bp = h + ((long)b * K + k0 + kb) * F + f0 + fB;
  int kc0 = kb >> 3;

#define PLA(r0, r1, st) { r0 = *(const uint4*)(Ap0 + (st) * 64); \
                          r1 = *(const uint4*)(Ap1 + (st) * 64); }
#define PLB(rb, st) { _Pragma("unroll") \
                      for (int i = 0; i < 16; ++i) rb[i] = Bp[(long)((st) * 64 + i) * F]; }
#define PSA(r0, r1) { *(uint4*)(As + am0 * 64 + ((ak ^ (am0 & 7)) * 8)) = r0; \
                      *(uint4*)(As + am1 * 64 + ((ak ^ (am1 & 7)) * 8)) = r1; }
#define PSB(rb) { *(uint4*)(Bs + fB * 64 + ((kc0 ^ (fB & 7)) * 8)) = *(uint4*)&rb[0]; \
                  *(uint4*)(Bs + fB * 64 + (((kc0 + 1) ^ (fB & 7)) * 8)) = *(uint4*)&rb[8]; }
#define PMM() { _Pragma("unroll") for (int ks = 0; ks < 2; ++ks) { \
    int kq = ks * 4 + quad; \
    bf16x8 bfr[4]; \
    _Pragma("unroll") for (int ft = 0; ft < 4; ++ft) { int fl = ft * 16 + lf; \
      bfr[ft] = *(const bf16x8*)(Bs + fl * 64 + ((kq ^ (fl & 7)) * 8)); } \
    int ml = w * 16 + lf; \
    bf16x8 afr = *(const bf16x8*)(As + ml * 64 + ((kq ^ (ml & 7)) * 8)); \
    _Pragma("unroll") for (int ft = 0; ft < 4; ++ft) \
      acc[ft] = __builtin_amdgcn_mfma_f32_16x16x32_bf16(afr, bfr[ft], acc[ft], 0, 0, 0); } }

  f32x4 acc[4];
#pragma unroll
  for (int ft = 0; ft < 4; ++ft) acc[ft] = (f32x4){0.f, 0.f, 0.f, 0.f};

  uint4 ra0, ra1, sa0, sa1;
  ushort_t rb[16], sb[16];
  PLA(ra0, ra1, 0); PLB(rb, 0);
  for (int s = 0; s < nsteps; s += 2) {
    // prefetch step s+1 into shadow regs (loads survive the barriers; only
    // lgkmcnt must drain for ds_write visibility)
    PLA(sa0, sa1, s + 1); PLB(sb, s + 1);
    __syncthreads();                 // prev MFMA done reading LDS
    PSA(ra0, ra1); PSB(rb);
    __syncthreads();
    PMM();
    if (s + 2 < nsteps) { PLA(ra0, ra1, s + 2); PLB(rb, s + 2); }
    __syncthreads();
    PSA(sa0, sa1); PSB(sb);
    __syncthreads();
    PMM();
  }
#undef PLA
#undef PLB
#undef PSA
#undef PSB
#undef PMM

#pragma unroll
  for (int r = 0; r < 4; ++r) {
    int m = m0 + w * 16 + quad * 4 + r;
    float* op = out + ((long)(b * M + m)) * F + f0 + lf;
#pragma unroll
    for (int ft = 0; ft < 4; ++ft) {
      if (ATOMIC) atomicAdd(op + ft * 16, acc[ft][r]);
      else        op[ft * 16] = acc[ft][r];
    }
  }
}

// ---------- fused head: hp3 fp32 [B][64][64][T] -> elu(W1) -> tanh(W2) -> d_out ----------
__global__ __launch_bounds__(256) void k_head(const float* hp3, const ushort_t* W1t,
    const ushort_t* W2t, const float* bias, void* outp, const int* flagp) {
  __shared__ __align__(16) ushort_t Ws1[128 * 64];
  __shared__ __align__(16) ushort_t Ws2[64 * 128];
  __shared__ __align__(16) ushort_t Is[64 * 64];
  __shared__ __align__(16) ushort_t G[64 * 128];
  int tid = threadIdx.x;
  int w = tid >> 6, l = tid & 63;
  int lf = l & 15, quad = l >> 4;
  int t0 = blockIdx.x * 64;
  int n = blockIdx.y, b = blockIdx.z;
  // stage W1t [128][64] and W2t [64][128]
  {
    const uint4* g1 = (const uint4*)W1t;
    for (int s = tid; s < 1024; s += 256) {
      int o = s >> 3, kg = s & 7;
      *(uint4*)(Ws1 + o * 64 + ((kg ^ (o & 7)) * 8)) = g1[s];
    }
    const uint4* g2 = (const uint4*)W2t;
    for (int s = tid; s < 1024; s += 256) {
      int o = s >> 4, kg = s & 15;
      *(uint4*)(Ws2 + o * 128 + ((kg ^ (o & 7)) * 8)) = g2[s];
    }
  }
  // stage Is [64t][64c] from hp3
  {
    int t = tid & 63;
    bool tok = (t0 + t) < T;
    const float* ip = hp3 + ((long)(b * 64 + n) * 64) * T + t0;
    for (int kg = tid >> 6; kg < 8; kg += 4) {
      ushort_t r[8];
#pragma unroll
      for (int j = 0; j < 8; ++j)
        r[j] = tok ? f2bfu(ip[(kg * 8 + j) * T + t]) : (ushort_t)0;
      *(uint4*)(Is + t * 64 + ((kg ^ (t & 7)) * 8)) = *(uint4*)r;
    }
  }
  __syncthreads();
  int tr = w * 16 + lf;
  // MFMA1: 64 -> 128, elu, into G
  {
    f32x4 a1[8];
#pragma unroll
    for (int mt = 0; mt < 8; ++mt) a1[mt] = (f32x4){0.f, 0.f, 0.f, 0.f};
#pragma unroll
    for (int kc = 0; kc < 2; ++kc) {
      int kg0 = kc * 4 + quad;
      bf16x8 bfr = *(const bf16x8*)(Is + tr * 64 + ((kg0 ^ (tr & 7)) * 8));
#pragma unroll
      for (int mt = 0; mt < 8; ++mt) {
        int o = mt * 16 + lf;
        bf16x8 afr = *(const bf16x8*)(Ws1 + o * 64 + ((kg0 ^ (o & 7)) * 8));
        a1[mt] = __builtin_amdgcn_mfma_f32_16x16x32_bf16(afr, bfr, a1[mt], 0, 0, 0);
      }
    }
    int tG = w * 16 + lf;
#pragma unroll
    for (int mt = 0; mt < 8; ++mt) {
#pragma unroll
      for (int r = 0; r < 4; ++r) {
        int o1 = mt * 16 + quad * 4 + r;
        float v = a1[mt][r] + bias[112 + o1];
        v = v > 0.f ? v : (expf(v) - 1.f);
        G[tG * 128 + ((o1 >> 3) ^ (tG & 7)) * 8 + (o1 & 7)] = f2bfu(v);
      }
    }
  }
  __syncthreads();
  // MFMA2: 128 -> 64, tanh, store
  {
    f32x4 a2[4];
#pragma unroll
    for (int mt = 0; mt < 4; ++mt) a2[mt] = (f32x4){0.f, 0.f, 0.f, 0.f};
#pragma unroll
    for (int kc = 0; kc < 4; ++kc) {
      int kg0 = kc * 4 + quad;
      bf16x8 bfr = *(const bf16x8*)(G + tr * 128 + ((kg0 ^ (tr & 7)) * 8));
#pragma unroll
      for (int mt = 0; mt < 4; ++mt) {
        int o = mt * 16 + lf;
        bf16x8 afr = *(const bf16x8*)(Ws2 + o * 128 + ((kg0 ^ (o & 7)) * 8));
        a2[mt] = __builtin_amdgcn_mfma_f32_16x16x32_bf16(afr, bfr, a2[mt], 0, 0, 0);
      }
    }
    int t = t0 + w * 16 + lf;
    if (t < T) {
      int bf = *flagp;
      long nb = (long)(b * 64 + n) * 64;
#pragma unroll
      for (int mt = 0; mt < 4; ++mt) {
#pragma unroll
        for (int r = 0; r < 4; ++r) {
          int o2 = mt * 16 + quad * 4 + r;
          float v = tanhf(a2[mt][r] + bias[240 + o2]);
          long idx = (nb + o2) * T + t;
          if (bf) ((bf16*)outp)[idx] = __float2bfloat16(v);
          else    ((float*)outp)[idx] = v;
        }
      }
    }
  }
}

extern "C" void kernel_launch(void* const* d_in, const int* in_sizes, int n_in,
                              void* d_out, int out_size, void* d_ws, size_t ws_size,
                              hipStream_t stream) {
  const int* ei0 = (const int*)d_in[1];
  const int* ei1 = (const int*)d_in[3];
  const int* ei2 = (const int*)d_in[5];

  char* base = (char*)d_ws;
  int* I = (int*)base;
  int* cnt0 = I;         int* off0 = I + 2048;  int* cur0 = I + 4112;  int* el0 = I + 6160;
  int* cnt1 = I + 22544; int* off1 = I + 23056; int* cur1 = I + 23584; int* el1 = I + 24096;
  int* cnt2 = I + 32288; int* off2 = I + 32416; int* cur2 = I + 32560; int* el2 = I + 32688;
  const int* flagp = (const int*)(base + O_FLAG);
  float* wc1f = (float*)(base + O_WC1);
  float* bias = (float*)(base + O_BIAS);
  float* bw0 = (float*)(base + O_BW0);
  float* bw1 = (float*)(base + O_BW1);
  float* bw2 = (float*)(base + O_BW2);
  ushort_t* Pb1 = (ushort_t*)(base + O_PB1);
  ushort_t* Pb2 = (ushort_t*)(base + O_PB2);
  ushort_t* Pb3 = (ushort_t*)(base + O_PB3);
  ushort_t* wt2 = (ushort_t*)(base + O_WT2);
  ushort_t* wt3 = (ushort_t*)(base + O_WT3);
  ushort_t* w1t = (ushort_t*)(base + O_W1H);
  ushort_t* w2t = (ushort_t*)(base + O_W2H);
  char* Aa = base + O_AA;
  char* Bb = base + O_BB;

  InPtrs P = { d_in[2], d_in[4], d_in[6], d_in[19], d_in[20], d_in[21],
               d_in[8], d_in[9], d_in[12], d_in[13], d_in[16], d_in[17],
               d_in[22], d_in[24], d_in[10], d_in[14], d_in[18], d_in[23],
               d_in[25], d_in[7], d_in[11], d_in[15] };

  k_setup0<<<159, 256, 0, stream>>>(I, (const ushort_t*)d_in[2]);
  k_prep<<<4594, 256, 0, stream>>>(P, base);
  k_hist3<<<64, 256, 0, stream>>>(ei0 + E0, ei1 + E1, ei2 + E2, cnt0, cnt1, cnt2);
  k_scan3<<<3, 64, 0, stream>>>(cnt0, off0, cur0, cnt1, off1, cur1, cnt2, off2, cur2);
  k_fill3<<<64, 256, 0, stream>>>(ei0 + E0, cur0, el0, ei1 + E1, cur1, el1, ei2 + E2, cur2, el2);

  // level 0 -> 1: h1 bf16 (Bb), pool1 (split-K=2, atomic, XCD-swizzled) -> hp1 fp32 (Aa)
  hipMemsetAsync(Aa, 0, (size_t)13107200, stream);   // zero hp1 for atomic accumulation
  k_gc1<<<dim3(1, N0, B), 256, 0, stream>>>(d_in[0], ei0, off0, el0, cnt0, bw0, wc1f, bias, (bf16*)Bb, flagp);
  k_poolp<2, true, true><<<1600, 256, 0, stream>>>(Pb1, (const ushort_t*)Bb, (float*)Aa, 512, 2048, 3200, 32);
  // level 1 -> 2: fused gather+cmix -> h2 bf16 (Bb), pool2 -> hp2 fp32 (Aa)
  k_gcm<16, 4, 32><<<dim3(4, N1, B), 256, 0, stream>>>((const float*)Aa, ei1, off1, el1, cnt1, bw1, wt2, bias + 16, (bf16*)Bb, N1);
  hipMemsetAsync(Aa, 0, (size_t)6553600, stream);    // zero hp2 (after gcm2 consumed hp1)
  k_poolp<2, true, true><<<800, 256, 0, stream>>>(Pb2, (const ushort_t*)Bb, (float*)Aa, 128, 512, 6400, 8);
  // level 2 -> 3: fused gather+cmix -> h3 bf16 (Bb), pool3 -> hp3 fp32 (Aa)
  k_gcm<32, 8, 64><<<dim3(4, N2, B), 256, 0, stream>>>((const float*)Aa, ei2, off2, el2, cnt2, bw2, wt3, bias + 48, (bf16*)Bb, N2);
  k_poolp<1, false, false><<<400, 256, 0, stream>>>(Pb3, (const ushort_t*)Bb, (float*)Aa, 64, 128, 12800, 2);
  // fused head -> d_out
  k_head<<<dim3(4, N3, B), 256, 0, stream>>>((const float*)Aa, w1t, w2t, bias, d_out, flagp);
}

// Round 2
// 283.712 us; speedup vs baseline: 1.0660x; 1.0660x over previous
//
#include <hip/hip_runtime.h>
#include <hip/hip_bf16.h>

using bf16 = __hip_bfloat16;
typedef unsigned short ushort_t;
typedef unsigned int uint_t;

constexpr int B = 2, T = 200;
constexpr int N0 = 2048, N1 = 512, N2 = 128, N3 = 64;
constexpr int E0 = 16384, E1 = 8192, E2 = 2048;

typedef __attribute__((ext_vector_type(8))) short bf16x8;
typedef __attribute__((ext_vector_type(4))) float f32x4;

// ---- workspace byte offsets (shared host/device) ----
constexpr size_t O_FLAG = 161792;   // int flag (outside the zeroed 40448-int region)
constexpr size_t O_WC1  = 163840;   // 64 f
constexpr size_t O_BIAS = 164096;   // 304 f: b1@0 b2@16 b3@48 b1h@112 b2h@240
constexpr size_t O_BW0  = 165312;   // 49152 f
constexpr size_t O_BW1  = 361920;   // 24576 f
constexpr size_t O_BW2  = 460224;   // 6144 f
constexpr size_t O_PB1  = 484800;   // 1048576 u16
constexpr size_t O_PB2  = 2581952;  // 65536 u16
constexpr size_t O_PB3  = 2713024;  // 8192 u16
constexpr size_t O_WT2  = 2729408;  // 2048 u16  [O=32][C=64]
constexpr size_t O_WT3  = 2733504;  // 8192 u16  [O=64][C=128]
constexpr size_t O_W1H  = 2749888;  // 8192 u16  [O=128][C=64]
constexpr size_t O_W2H  = 2766272;  // 8192 u16  [O=64][C=128]
constexpr size_t O_AA   = 2785280;  // arena A 13,107,200 B (fp32 hp)
constexpr size_t O_BB   = 15892480; // arena B 26,214,400 B (bf16 h)

__device__ __forceinline__ float ldx(const void* p, long i, int bf) {
  if (bf) {
    uint_t v = (uint_t)(((const ushort_t*)p)[i]) << 16;
    float f; __builtin_memcpy(&f, &v, 4); return f;
  }
  return ((const float*)p)[i];
}
__device__ __forceinline__ void stf(float* p, float v) { *p = v; }
__device__ __forceinline__ void stf(bf16* p, float v) { *p = __float2bfloat16(v); }
__device__ __forceinline__ ushort_t f2bfu(float v) {
  bf16 h = __float2bfloat16(v); ushort_t u; __builtin_memcpy(&u, &h, 2); return u;
}

struct InPtrs {
  const void* ea0; const void* ea1; const void* ea2;
  const void* P01; const void* P12; const void* P23;
  const void* Wk1; const void* Wr1; const void* Wk2; const void* Wr2;
  const void* Wk3; const void* Wr3; const void* W1h; const void* W2h;
  const void* b1; const void* b2; const void* b3; const void* b1h; const void* b2h;
  const void* A1; const void* A2; const void* A3;
};

// ---------- setup0: zero CSR ints (blocks 0..157) + dtype probe (block 158) ----------
__global__ void k_setup0(int* I, const ushort_t* ea) {
  if (blockIdx.x < 158) {
    int i = blockIdx.x * 256 + threadIdx.x;
    I[i] = 0;                      // covers 40448 ints exactly
  } else if (threadIdx.x == 0) {
    int c = 0;
    for (int i = 0; i < 128; ++i) {
      uint_t v = (uint_t)ea[i] << 16;
      float f; __builtin_memcpy(&f, &v, 4);
      if (f >= 0.f && f <= 1.0f) c++;
    }
    *(int*)((char*)I + O_FLAG) = (c >= 120) ? 1 : 0;
  }
}

__device__ __forceinline__ void bw_one(const void* ea, int bf, const void* A,
                                       float* bw, int e) {
  float a0 = ldx(ea, e*3+0, bf), a1 = ldx(ea, e*3+1, bf), a2 = ldx(ea, e*3+2, bf);
  float l0 = a0*ldx(A,0,bf) + a1*ldx(A,3,bf) + a2*ldx(A,6,bf);
  float l1 = a0*ldx(A,1,bf) + a1*ldx(A,4,bf) + a2*ldx(A,7,bf);
  float l2 = a0*ldx(A,2,bf) + a1*ldx(A,5,bf) + a2*ldx(A,8,bf);
  float m = fmaxf(l0, fmaxf(l1, l2));
  float x0 = expf(l0 - m), x1 = expf(l1 - m), x2 = expf(l2 - m);
  float inv = 1.0f / (x0 + x1 + x2);
  bw[e*3+0] = x0*inv; bw[e*3+1] = x1*inv; bw[e*3+2] = x2*inv;
}

// ---------- fat prep kernel: edge softmax, P->bf16, W transposes, params ----------
__global__ void k_prep(InPtrs P, char* base) {
  int bf = *(const int*)(base + O_FLAG);
  int bx = blockIdx.x, tid = threadIdx.x;
  float* bw0 = (float*)(base + O_BW0);
  float* bw1 = (float*)(base + O_BW1);
  float* bw2 = (float*)(base + O_BW2);
  if (bx < 64)        { bw_one(P.ea0, bf, P.A1, bw0, bx*256+tid); return; }
  if (bx < 96)        { bw_one(P.ea1, bf, P.A2, bw1, (bx-64)*256+tid); return; }
  if (bx < 104)       { bw_one(P.ea2, bf, P.A3, bw2, (bx-96)*256+tid); return; }
  if (bx < 4200)      { long i = (long)(bx-104)*256+tid;
                        ((ushort_t*)(base+O_PB1))[i] = f2bfu(ldx(P.P01, i, bf)); return; }
  if (bx < 4456)      { int i = (bx-4200)*256+tid;
                        ((ushort_t*)(base+O_PB2))[i] = f2bfu(ldx(P.P12, i, bf)); return; }
  if (bx < 4488)      { int i = (bx-4456)*256+tid;
                        ((ushort_t*)(base+O_PB3))[i] = f2bfu(ldx(P.P23, i, bf)); return; }
  if (bx < 4496)      { int j = (bx-4488)*256+tid; int o = j>>6, c = j&63;
                        float v = (c<48) ? ldx(P.Wk2, c*32+o, bf) : ldx(P.Wr2, (c-48)*32+o, bf);
                        ((ushort_t*)(base+O_WT2))[j] = f2bfu(v); return; }
  if (bx < 4528)      { int j = (bx-4496)*256+tid; int o = j>>7, c = j&127;
                        float v = (c<96) ? ldx(P.Wk3, c*64+o, bf) : ldx(P.Wr3, (c-96)*64+o, bf);
                        ((ushort_t*)(base+O_WT3))[j] = f2bfu(v); return; }
  if (bx < 4560)      { int j = (bx-4528)*256+tid; int o = j>>6, c = j&63;
                        ((ushort_t*)(base+O_W1H))[j] = f2bfu(ldx(P.W1h, c*128+o, bf)); return; }
  if (bx < 4592)      { int j = (bx-4560)*256+tid; int o = j>>7, c = j&127;
                        ((ushort_t*)(base+O_W2H))[j] = f2bfu(ldx(P.W2h, c*64+o, bf)); return; }
  { // params: wc1 (64) + biases (304)
    int i = (bx-4592)*256+tid;
    if (i < 64) {
      ((float*)(base+O_WC1))[i] = (i<48) ? ldx(P.Wk1, i, bf) : ldx(P.Wr1, i-48, bf);
    } else if (i < 368) {
      int j = i - 64; float v;
      if (j < 16)       v = ldx(P.b1, j, bf);
      else if (j < 48)  v = ldx(P.b2, j-16, bf);
      else if (j < 112) v = ldx(P.b3, j-48, bf);
      else if (j < 240) v = ldx(P.b1h, j-112, bf);
      else              v = ldx(P.b2h, j-240, bf);
      ((float*)(base+O_BIAS))[j] = v;
    }
  }
}

__global__ void k_hist3(const int* d0, const int* d1, const int* d2,
                        int* c0, int* c1, int* c2) {
  int i = blockIdx.x * 256 + threadIdx.x;
  if (i < E0) atomicAdd(&c0[d0[i]], 1);
  if (i < E1) atomicAdd(&c1[d1[i]], 1);
  if (i < E2) atomicAdd(&c2[d2[i]], 1);
}

__global__ void k_scan3(const int* c0, int* o0, int* u0,
                        const int* c1, int* o1, int* u1,
                        const int* c2, int* o2, int* u2) {
  const int* cnt; int* off; int* cur; int N;
  if (blockIdx.x == 0)      { cnt = c0; off = o0; cur = u0; N = N0; }
  else if (blockIdx.x == 1) { cnt = c1; off = o1; cur = u1; N = N1; }
  else                      { cnt = c2; off = o2; cur = u2; N = N2; }
  int tid = threadIdx.x;
  int chunk = (N + 63) >> 6;
  int base = tid * chunk;
  int s = 0;
  for (int j = 0; j < chunk; ++j) { int idx = base + j; if (idx < N) s += cnt[idx]; }
  int pre = s;
  for (int d = 1; d < 64; d <<= 1) {
    int v = __shfl_up(pre, d, 64);
    if (tid >= d) pre += v;
  }
  int run = pre - s;
  for (int j = 0; j < chunk; ++j) {
    int idx = base + j;
    if (idx < N) { off[idx] = run; cur[idx] = run; run += cnt[idx]; }
  }
  if (tid == 63) off[N] = run;
}

__global__ void k_fill3(const int* d0, int* u0, int* e0l,
                        const int* d1, int* u1, int* e1l,
                        const int* d2, int* u2, int* e2l) {
  int i = blockIdx.x * 256 + threadIdx.x;
  if (i < E0) { int p = atomicAdd(&u0[d0[i]], 1); e0l[p] = i; }
  if (i < E1) { int p = atomicAdd(&u1[d1[i]], 1); e1l[p] = i; }
  if (i < E2) { int p = atomicAdd(&u2[d2[i]], 1); e2l[p] = i; }
}

// ---------- fused level-1 gather + channel-mix (Cin=1 -> 16), raw x via ldx ----------
// edge data staged in LDS per block (chunks of 32, uniform trip count)
__global__ __launch_bounds__(256) void k_gc1(const void* x, const int* src,
    const int* off, const int* elist, const int* cnt, const float* bw,
    const float* W, const float* bias, bf16* h1, const int* flagp) {
  __shared__ float Wl[64];
  __shared__ float bl[16];
  __shared__ float ew0[32], ew1[32], ew2[32];
  __shared__ int es[32];
  int tid = threadIdx.x;
  if (tid < 64) Wl[tid] = W[tid];
  if (tid < 16) bl[tid] = bias[tid];
  int bf = *flagp;
  int n = blockIdx.y, b = blockIdx.z;
  int t = tid;
  bool tok = t < T;
  int beg = off[n], end = off[n + 1];
  float a0 = 0.f, a1 = 0.f, a2 = 0.f;
  for (int q0 = beg; q0 < end; q0 += 32) {
    int m = end - q0; if (m > 32) m = 32;
    __syncthreads();
    if (tid < m) {
      int e = elist[q0 + tid];
      es[tid] = src[e];
      ew0[tid] = bw[e*3+0]; ew1[tid] = bw[e*3+1]; ew2[tid] = bw[e*3+2];
    }
    __syncthreads();
    if (tok) {
      for (int j = 0; j < m; ++j) {
        float xv = ldx(x, (long)(b * N0 + es[j]) * T + t, bf);
        a0 += ew0[j] * xv; a1 += ew1[j] * xv; a2 += ew2[j] * xv;
      }
    }
  }
  __syncthreads();   // Wl/bl visibility even when the edge loop has 0 iterations
  if (!tok) return;
  int c = cnt[n];
  float inv = 1.f / (float)(c > 0 ? c : 1);
  a0 *= inv; a1 *= inv; a2 *= inv;
  float xr = ldx(x, (long)(b * N0 + n) * T + t, bf);
  bf16* op = h1 + ((long)(b * N0 + n) * 16) * T + t;
#pragma unroll
  for (int o = 0; o < 16; ++o) {
    float v = a0 * Wl[o] + a1 * Wl[16 + o] + a2 * Wl[32 + o] + xr * Wl[48 + o] + bl[o];
    v = v > 0.f ? v : (expf(v) - 1.f);
    op[o * T] = __float2bfloat16(v);
  }
}

// ---------- fused gather + MFMA channel-mix (levels 2,3) ----------
// hp fp32 [B][N][CIN][T] -> h bf16 [B][N][O][T];  C=4*CIN
template<int CIN, int CPI, int O>
__global__ __launch_bounds__(256) void k_gcm(const float* hp, const int* src,
    const int* off, const int* elist, const int* cnt, const float* bw,
    const ushort_t* Wt, const float* bias, bf16* h, int N) {
  constexpr int C = 4 * CIN;
  constexpr int KG = C / 8;
  constexpr int MT = O / 16;
  __shared__ __align__(16) ushort_t Ws[O * C];
  __shared__ __align__(16) ushort_t Is[64 * C];
  __shared__ float ew0[32], ew1[32], ew2[32];
  __shared__ int es[32];
  int tid = threadIdx.x;
  int w = tid >> 6, l = tid & 63;
  int lf = l & 15, quad = l >> 4;
  int t0 = blockIdx.x * 64;
  int n = blockIdx.y, b = blockIdx.z;
  // stage W
  {
    const uint4* Wg = (const uint4*)Wt;
    for (int s = tid; s < O * KG; s += 256) {
      int o = s / KG, kg = s % KG;
      *(uint4*)(Ws + o * C + ((kg ^ (o & 7)) * 8)) = Wg[s];
    }
  }
  // gather into registers, edge data staged in LDS
  int tx = tid & 63, iy = tid >> 6;
  int t = t0 + tx;
  bool tok = t < T;
  float acc[3][CPI], xr[CPI];
#pragma unroll
  for (int k = 0; k < 3; ++k)
#pragma unroll
    for (int j = 0; j < CPI; ++j) acc[k][j] = 0.f;
#pragma unroll
  for (int j = 0; j < CPI; ++j) xr[j] = 0.f;
  int beg = off[n], end = off[n + 1];
  for (int q0 = beg; q0 < end; q0 += 32) {
    int mE = end - q0; if (mE > 32) mE = 32;
    __syncthreads();
    if (tid < mE) {
      int e = elist[q0 + tid];
      es[tid] = src[e];
      ew0[tid] = bw[e*3+0]; ew1[tid] = bw[e*3+1]; ew2[tid] = bw[e*3+2];
    }
    __syncthreads();
    if (tok) {
      for (int j2 = 0; j2 < mE; ++j2) {
        int s = es[j2];
        float w0 = ew0[j2], w1 = ew1[j2], w2 = ew2[j2];
        const float* xp = hp + ((long)(b * N + s) * CIN) * T + t;
#pragma unroll
        for (int j = 0; j < CPI; ++j) {
          float xv = xp[(iy * CPI + j) * T];
          acc[0][j] += w0 * xv; acc[1][j] += w1 * xv; acc[2][j] += w2 * xv;
        }
      }
    }
  }
  float inv = 1.f;
  if (tok) {
    int c = cnt[n];
    inv = 1.f / (float)(c > 0 ? c : 1);
    const float* xs = hp + ((long)(b * N + n) * CIN) * T + t;
#pragma unroll
    for (int j = 0; j < CPI; ++j) xr[j] = xs[(iy * CPI + j) * T];
  }
  // dump z|x into swizzled Is (bf16 scalars)
#pragma unroll
  for (int j = 0; j < CPI; ++j) {
    int i = iy * CPI + j;
#pragma unroll
    for (int k = 0; k < 3; ++k) {
      int c = k * CIN + i;
      Is[tx * C + ((c >> 3) ^ (tx & 7)) * 8 + (c & 7)] = f2bfu(acc[k][j] * inv);
    }
    int c = 3 * CIN + i;
    Is[tx * C + ((c >> 3) ^ (tx & 7)) * 8 + (c & 7)] = f2bfu(xr[j]);
  }
  __syncthreads();
  // MFMA
  f32x4 dacc[MT];
#pragma unroll
  for (int mt = 0; mt < MT; ++mt) dacc[mt] = (f32x4){0.f, 0.f, 0.f, 0.f};
  int tr = w * 16 + lf;
#pragma unroll
  for (int kc = 0; kc < C / 32; ++kc) {
    int kg0 = kc * 4 + quad;
    bf16x8 bfr = *(const bf16x8*)(Is + tr * C + ((kg0 ^ (tr & 7)) * 8));
#pragma unroll
    for (int mt = 0; mt < MT; ++mt) {
      int o = mt * 16 + lf;
      bf16x8 afr = *(const bf16x8*)(Ws + o * C + ((kg0 ^ (o & 7)) * 8));
      dacc[mt] = __builtin_amdgcn_mfma_f32_16x16x32_bf16(afr, bfr, dacc[mt], 0, 0, 0);
    }
  }
  int tg = t0 + w * 16 + lf;
  if (tg < T) {
    long nb = (long)(b * N + n) * O;
#pragma unroll
    for (int mt = 0; mt < MT; ++mt) {
#pragma unroll
      for (int r = 0; r < 4; ++r) {
        int o = mt * 16 + quad * 4 + r;
        float v = dacc[mt][r] + bias[o];
        v = v > 0.f ? v : (expf(v) - 1.f);
        h[(nb + o) * T + tg] = __float2bfloat16(v);
      }
    }
  }
}

// ---------- pipelined pool GEMM: out[b,m,f] = sum_k Pb[m,k] * h[b,k,f] ----------
// BM=64, BN=64. Register prefetch 2 steps ahead + LDS double-buffer with RAW
// s_barrier (no vmcnt drain!) so loads stay in flight across barriers (T3/T4).
// One barrier per K-step. grid.x = (F/64) * nInner, nInner = (M/64)*B.
template<bool SWZ>
__global__ __launch_bounds__(256) void k_poolp(const ushort_t* Pb, const ushort_t* h,
                                               float* out, int M, int K, int F, int nInner) {
  __shared__ __align__(16) ushort_t As0[64 * 64];
  __shared__ __align__(16) ushort_t As1[64 * 64];
  __shared__ __align__(16) ushort_t Bs0[64 * 64];
  __shared__ __align__(16) ushort_t Bs1[64 * 64];
  int tid = threadIdx.x;
  int w = tid >> 6, l = tid & 63;
  int lf = l & 15, quad = l >> 4;
  int v = blockIdx.x;
  if (SWZ) { int q = gridDim.x >> 3; v = (v & 7) * q + (v >> 3); }  // f-chunk per XCD
  int f_blk = v / nInner; int rem = v % nInner;
  int m_blk = rem >> 1;
  int b = rem & 1;
  int f0 = f_blk * 64, m0 = m_blk * 64;
  int nsteps = K >> 6;   // 32 / 8 / 2 — always even

  // per-thread staging addresses
  int am0 = tid >> 3, ak = tid & 7;        // A rows: 2 uint4/thread
  int am1 = am0 + 32;
  const ushort_t* Ap0 = Pb + (long)(m0 + am0) * K + ak * 8;
  const ushort_t* Ap1 = Pb + (long)(m0 + am1) * K + ak * 8;
  int fB = tid & 63, kb = (tid >> 6) * 16; // B: 16 scalar ushort/thread (f fixed, k strided)
  const ushort_t* Bp = h + ((long)b * K + kb) * F + f0 + fB;
  int kc0 = kb >> 3;

#define PLA(r0, r1, st) { r0 = *(const uint4*)(Ap0 + (long)(st) * 64); \
                          r1 = *(const uint4*)(Ap1 + (long)(st) * 64); }
#define PLB(rb, st) { _Pragma("unroll") \
                      for (int i = 0; i < 16; ++i) rb[i] = Bp[((long)(st) * 64 + i) * F]; }
#define PSA(S, r0, r1) { *(uint4*)(S + am0 * 64 + ((ak ^ (am0 & 7)) * 8)) = r0; \
                         *(uint4*)(S + am1 * 64 + ((ak ^ (am1 & 7)) * 8)) = r1; }
#define PSB(S, rb) { *(uint4*)(S + fB * 64 + ((kc0 ^ (fB & 7)) * 8)) = *(uint4*)&rb[0]; \
                     *(uint4*)(S + fB * 64 + (((kc0 + 1) ^ (fB & 7)) * 8)) = *(uint4*)&rb[8]; }
#define PMM(SA, SB) { _Pragma("unroll") for (int ks = 0; ks < 2; ++ks) { \
    int kq = ks * 4 + quad; \
    bf16x8 bfr[4]; \
    _Pragma("unroll") for (int ft = 0; ft < 4; ++ft) { int fl = ft * 16 + lf; \
      bfr[ft] = *(const bf16x8*)(SB + fl * 64 + ((kq ^ (fl & 7)) * 8)); } \
    int ml = w * 16 + lf; \
    bf16x8 afr = *(const bf16x8*)(SA + ml * 64 + ((kq ^ (ml & 7)) * 8)); \
    _Pragma("unroll") for (int ft = 0; ft < 4; ++ft) \
      acc[ft] = __builtin_amdgcn_mfma_f32_16x16x32_bf16(afr, bfr[ft], acc[ft], 0, 0, 0); } }
// raw barrier: lgkm drain for ds_write visibility, NO vmcnt drain (prefetch
// loads stay in flight — this is the whole point vs __syncthreads)
#define BARW() { asm volatile("s_waitcnt lgkmcnt(0)" ::: "memory"); \
                 __builtin_amdgcn_s_barrier(); \
                 asm volatile("" ::: "memory"); }

  f32x4 acc[4];
#pragma unroll
  for (int ft = 0; ft < 4; ++ft) acc[ft] = (f32x4){0.f, 0.f, 0.f, 0.f};

  uint4 xa0, xa1, ya0, ya1;
  ushort_t xb[16], yb[16];
  // prologue: X <- step0, Y <- step1 (nsteps >= 2 always); step0 -> buf0
  PLA(xa0, xa1, 0); PLB(xb, 0);
  PLA(ya0, ya1, 1); PLB(yb, 1);
  PSA(As0, xa0, xa1); PSB(Bs0, xb);
  BARW();
  for (int e = 0; e < nsteps; e += 2) {
    // first half: compute step e from buf0; Y holds step e+1
    if (e + 2 < nsteps) { PLA(xa0, xa1, e + 2); PLB(xb, e + 2); }
    PMM(As0, Bs0);
    PSA(As1, ya0, ya1); PSB(Bs1, yb);   // buf1 reads finished at end of e-1
    BARW();
    // second half: compute step e+1 from buf1; X holds step e+2
    if (e + 3 < nsteps) { PLA(ya0, ya1, e + 3); PLB(yb, e + 3); }
    PMM(As1, Bs1);
    if (e + 2 < nsteps) { PSA(As0, xa0, xa1); PSB(Bs0, xb); }
    BARW();
  }
#undef PLA
#undef PLB
#undef PSA
#undef PSB
#undef PMM
#undef BARW

#pragma unroll
  for (int r = 0; r < 4; ++r) {
    int m = m0 + w * 16 + quad * 4 + r;
    float* op = out + ((long)(b * M + m)) * F + f0 + lf;
#pragma unroll
    for (int ft = 0; ft < 4; ++ft) op[ft * 16] = acc[ft][r];
  }
}

// ---------- fused head: hp3 fp32 [B][64][64][T] -> elu(W1) -> tanh(W2) -> d_out ----------
__global__ __launch_bounds__(256) void k_head(const float* hp3, const ushort_t* W1t,
    const ushort_t* W2t, const float* bias, void* outp, const int* flagp) {
  __shared__ __align__(16) ushort_t Ws1[128 * 64];
  __shared__ __align__(16) ushort_t Ws2[64 * 128];
  __shared__ __align__(16) ushort_t Is[64 * 64];
  __shared__ __align__(16) ushort_t G[64 * 128];
  int tid = threadIdx.x;
  int w = tid >> 6, l = tid & 63;
  int lf = l & 15, quad = l >> 4;
  int t0 = blockIdx.x * 64;
  int n = blockIdx.y, b = blockIdx.z;
  // stage W1t [128][64] and W2t [64][128]
  {
    const uint4* g1 = (const uint4*)W1t;
    for (int s = tid; s < 1024; s += 256) {
      int o = s >> 3, kg = s & 7;
      *(uint4*)(Ws1 + o * 64 + ((kg ^ (o & 7)) * 8)) = g1[s];
    }
    const uint4* g2 = (const uint4*)W2t;
    for (int s = tid; s < 1024; s += 256) {
      int o = s >> 4, kg = s & 15;
      *(uint4*)(Ws2 + o * 128 + ((kg ^ (o & 7)) * 8)) = g2[s];
    }
  }
  // stage Is [64t][64c] from hp3
  {
    int t = tid & 63;
    bool tok = (t0 + t) < T;
    const float* ip = hp3 + ((long)(b * 64 + n) * 64) * T + t0;
    for (int kg = tid >> 6; kg < 8; kg += 4) {
      ushort_t r[8];
#pragma unroll
      for (int j = 0; j < 8; ++j)
        r[j] = tok ? f2bfu(ip[(kg * 8 + j) * T + t]) : (ushort_t)0;
      *(uint4*)(Is + t * 64 + ((kg ^ (t & 7)) * 8)) = *(uint4*)r;
    }
  }
  __syncthreads();
  int tr = w * 16 + lf;
  // MFMA1: 64 -> 128, elu, into G
  {
    f32x4 a1[8];
#pragma unroll
    for (int mt = 0; mt < 8; ++mt) a1[mt] = (f32x4){0.f, 0.f, 0.f, 0.f};
#pragma unroll
    for (int kc = 0; kc < 2; ++kc) {
      int kg0 = kc * 4 + quad;
      bf16x8 bfr = *(const bf16x8*)(Is + tr * 64 + ((kg0 ^ (tr & 7)) * 8));
#pragma unroll
      for (int mt = 0; mt < 8; ++mt) {
        int o = mt * 16 + lf;
        bf16x8 afr = *(const bf16x8*)(Ws1 + o * 64 + ((kg0 ^ (o & 7)) * 8));
        a1[mt] = __builtin_amdgcn_mfma_f32_16x16x32_bf16(afr, bfr, a1[mt], 0, 0, 0);
      }
    }
    int tG = w * 16 + lf;
#pragma unroll
    for (int mt = 0; mt < 8; ++mt) {
#pragma unroll
      for (int r = 0; r < 4; ++r) {
        int o1 = mt * 16 + quad * 4 + r;
        float v = a1[mt][r] + bias[112 + o1];
        v = v > 0.f ? v : (expf(v) - 1.f);
        G[tG * 128 + ((o1 >> 3) ^ (tG & 7)) * 8 + (o1 & 7)] = f2bfu(v);
      }
    }
  }
  __syncthreads();
  // MFMA2: 128 -> 64, tanh, store
  {
    f32x4 a2[4];
#pragma unroll
    for (int mt = 0; mt < 4; ++mt) a2[mt] = (f32x4){0.f, 0.f, 0.f, 0.f};
#pragma unroll
    for (int kc = 0; kc < 4; ++kc) {
      int kg0 = kc * 4 + quad;
      bf16x8 bfr = *(const bf16x8*)(G + tr * 128 + ((kg0 ^ (tr & 7)) * 8));
#pragma unroll
      for (int mt = 0; mt < 4; ++mt) {
        int o = mt * 16 + lf;
        bf16x8 afr = *(const bf16x8*)(Ws2 + o * 128 + ((kg0 ^ (o & 7)) * 8));
        a2[mt] = __builtin_amdgcn_mfma_f32_16x16x32_bf16(afr, bfr, a2[mt], 0, 0, 0);
      }
    }
    int t = t0 + w * 16 + lf;
    if (t < T) {
      int bf = *flagp;
      long nb = (long)(b * 64 + n) * 64;
#pragma unroll
      for (int mt = 0; mt < 4; ++mt) {
#pragma unroll
        for (int r = 0; r < 4; ++r) {
          int o2 = mt * 16 + quad * 4 + r;
          float v = tanhf(a2[mt][r] + bias[240 + o2]);
          long idx = (nb + o2) * T + t;
          if (bf) ((bf16*)outp)[idx] = __float2bfloat16(v);
          else    ((float*)outp)[idx] = v;
        }
      }
    }
  }
}

extern "C" void kernel_launch(void* const* d_in, const int* in_sizes, int n_in,
                              void* d_out, int out_size, void* d_ws, size_t ws_size,
                              hipStream_t stream) {
  const int* ei0 = (const int*)d_in[1];
  const int* ei1 = (const int*)d_in[3];
  const int* ei2 = (const int*)d_in[5];

  char* base = (char*)d_ws;
  int* I = (int*)base;
  int* cnt0 = I;         int* off0 = I + 2048;  int* cur0 = I + 4112;  int* el0 = I + 6160;
  int* cnt1 = I + 22544; int* off1 = I + 23056; int* cur1 = I + 23584; int* el1 = I + 24096;
  int* cnt2 = I + 32288; int* off2 = I + 32416; int* cur2 = I + 32560; int* el2 = I + 32688;
  const int* flagp = (const int*)(base + O_FLAG);
  float* wc1f = (float*)(base + O_WC1);
  float* bias = (float*)(base + O_BIAS);
  float* bw0 = (float*)(base + O_BW0);
  float* bw1 = (float*)(base + O_BW1);
  float* bw2 = (float*)(base + O_BW2);
  ushort_t* Pb1 = (ushort_t*)(base + O_PB1);
  ushort_t* Pb2 = (ushort_t*)(base + O_PB2);
  ushort_t* Pb3 = (ushort_t*)(base + O_PB3);
  ushort_t* wt2 = (ushort_t*)(base + O_WT2);
  ushort_t* wt3 = (ushort_t*)(base + O_WT3);
  ushort_t* w1t = (ushort_t*)(base + O_W1H);
  ushort_t* w2t = (ushort_t*)(base + O_W2H);
  char* Aa = base + O_AA;
  char* Bb = base + O_BB;

  InPtrs P = { d_in[2], d_in[4], d_in[6], d_in[19], d_in[20], d_in[21],
               d_in[8], d_in[9], d_in[12], d_in[13], d_in[16], d_in[17],
               d_in[22], d_in[24], d_in[10], d_in[14], d_in[18], d_in[23],
               d_in[25], d_in[7], d_in[11], d_in[15] };

  k_setup0<<<159, 256, 0, stream>>>(I, (const ushort_t*)d_in[2]);
  k_prep<<<4594, 256, 0, stream>>>(P, base);
  k_hist3<<<64, 256, 0, stream>>>(ei0 + E0, ei1 + E1, ei2 + E2, cnt0, cnt1, cnt2);
  k_scan3<<<3, 64, 0, stream>>>(cnt0, off0, cur0, cnt1, off1, cur1, cnt2, off2, cur2);
  k_fill3<<<64, 256, 0, stream>>>(ei0 + E0, cur0, el0, ei1 + E1, cur1, el1, ei2 + E2, cur2, el2);

  // level 0 -> 1: h1 bf16 (Bb), pool1 -> hp1 fp32 (Aa)
  k_gc1<<<dim3(1, N0, B), 256, 0, stream>>>(d_in[0], ei0, off0, el0, cnt0, bw0, wc1f, bias, (bf16*)Bb, flagp);
  k_poolp<true><<<800, 256, 0, stream>>>(Pb1, (const ushort_t*)Bb, (float*)Aa, 512, 2048, 3200, 16);
  // level 1 -> 2: fused gather+cmix -> h2 bf16 (Bb), pool2 -> hp2 fp32 (Aa)
  k_gcm<16, 4, 32><<<dim3(4, N1, B), 256, 0, stream>>>((const float*)Aa, ei1, off1, el1, cnt1, bw1, wt2, bias + 16, (bf16*)Bb, N1);
  k_poolp<true><<<400, 256, 0, stream>>>(Pb2, (const ushort_t*)Bb, (float*)Aa, 128, 512, 6400, 4);
  // level 2 -> 3: fused gather+cmix -> h3 bf16 (Bb), pool3 -> hp3 fp32 (Aa)
  k_gcm<32, 8, 64><<<dim3(4, N2, B), 256, 0, stream>>>((const float*)Aa, ei2, off2, el2, cnt2, bw2, wt3, bias + 48, (bf16*)Bb, N2);
  k_poolp<false><<<400, 256, 0, stream>>>(Pb3, (const ushort_t*)Bb, (float*)Aa, 64, 128, 12800, 2);
  // fused head -> d_out
  k_head<<<dim3(4, N3, B), 256, 0, stream>>>((const float*)Aa, w1t, w2t, bias, d_out, flagp);
}